// Round 7
// baseline (226.776 us; speedup 1.0000x reference)
//
#include <hip/hip_runtime.h>
#include <math.h>

#define NEG_SLOPE 0.2f

typedef __attribute__((ext_vector_type(8))) _Float16 h8v;
typedef __attribute__((ext_vector_type(2))) _Float16 h2v;
typedef __attribute__((ext_vector_type(4))) float float4v;

__device__ __forceinline__ h2v u2h(unsigned u) { return __builtin_bit_cast(h2v, u); }
__device__ __forceinline__ unsigned h2u(h2v h) { return __builtin_bit_cast(unsigned, h); }
// RTNE pack of two f32 -> packed f16x2 (v_cvt_f16_f32 x2 + v_pack_b32_f16)
__device__ __forceinline__ unsigned pk16(float a, float b) {
  h2v r; r.x = (_Float16)a; r.y = (_Float16)b;
  return __builtin_bit_cast(unsigned, r);
}
__device__ __forceinline__ unsigned short f16b(float f) {
  return __builtin_bit_cast(unsigned short, (_Float16)f);
}
// f32 += f16x2 . f16x2  (v_dot2_f32_f16, one issue slot for 2 MACs)
__device__ __forceinline__ float fdot2(h2v a, h2v b, float c) {
#if __has_builtin(__builtin_amdgcn_fdot2)
  return __builtin_amdgcn_fdot2(a, b, c, false);
#else
  return fmaf((float)a.x, (float)b.x, fmaf((float)a.y, (float)b.y, c));
#endif
}

// 256-wide block exclusive scan; all 256 threads must call. ws: >=8 ints LDS.
__device__ __forceinline__ int block_scan256(int v, int tid, int* ws) {
  const int lane = tid & 63, w = tid >> 6;
  int incl = v;
#pragma unroll
  for (int off = 1; off < 64; off <<= 1) {
    int t = __shfl_up(incl, off);
    if (lane >= off) incl += t;
  }
  if (lane == 63) ws[w] = incl;
  __syncthreads();
  if (tid == 0) {
    int s = 0;
#pragma unroll
    for (int i = 0; i < 4; i++) { int t = ws[i]; ws[4 + i] = s; s += t; }
  }
  __syncthreads();
  return incl - v + ws[4 + w];
}

// ---------------------------------------------------------------------------
// Fused: blocks 0..19 pack the 4 weight matrices into MFMA B-fragment layout;
// blocks 20.. run the coarse bucket histogram (4096 edges/block).
// ---------------------------------------------------------------------------
__global__ __launch_bounds__(256) void pack_hist(
    const float* __restrict__ W1s, const float* __restrict__ W1d,
    const float* __restrict__ W2s, const float* __restrict__ W2d,
    unsigned short* __restrict__ B1s, unsigned short* __restrict__ B1d,
    unsigned short* __restrict__ B2s, unsigned short* __restrict__ B2d,
    const int* __restrict__ ei, int* __restrict__ bhist, int N, int E, int NB) {
  int blk = blockIdx.x;
  if (blk < 20) {
    const float* W; unsigned short* Bp; int C, base;
    if (blk < 8)       { W = W1s; Bp = B1s; C = 128; base = blk; }
    else if (blk < 16) { W = W1d; Bp = B1d; C = 128; base = blk - 8; }
    else if (blk < 18) { W = W2s; Bp = B2s; C = 32;  base = blk - 16; }
    else               { W = W2d; Bp = B2d; C = 32;  base = blk - 18; }
    int idx = base * 256 + threadIdx.x;
    int total = (C / 16) * 4 * 64;
    if (idx >= total) return;
    int lane = idx & 63;
    int kc = (idx >> 6) & 3;
    int t = idx >> 8;
    int n = t * 16 + (lane & 15);
    int k0 = kc * 32 + (lane >> 4) * 8;
    unsigned short* o = Bp + (size_t)idx * 8;
#pragma unroll
    for (int j = 0; j < 8; j++) o[j] = f16b(W[(size_t)(k0 + j) * C + n]);
    return;
  }
  blk -= 20;
  __shared__ int cnt[256];
  const int tid = threadIdx.x;
  cnt[tid] = 0;
  __syncthreads();
  const int base = blk * 4096;
  const int vn = min(4096, E - base);
#pragma unroll 4
  for (int j = 0; j < 16; j++) {
    int i = j * 256 + tid;
    if (i < vn) {
      int d = ei[E + base + i];
      d = min(max(d, 0), N - 1);
      atomicAdd(&cnt[d >> 8], 1);
    }
  }
  __syncthreads();
  if (tid < NB && cnt[tid]) atomicAdd(&bhist[tid], cnt[tid]);
}

// ---------------------------------------------------------------------------
// bucket_sort: local re-scan of bhist gives bbase (no bucket_scan kernel);
// global reservation via zero-based bcur_rel (covered by the bhist memset).
// ---------------------------------------------------------------------------
__global__ __launch_bounds__(256) void bucket_sort(
    const int* __restrict__ ei, const int* __restrict__ bhist,
    int* __restrict__ bcur_rel,
    unsigned int* __restrict__ pairs, int N, int E, int NB) {
  __shared__ int cnt[256];
  __shared__ int offs[256];
  __shared__ int gbase[256];
  __shared__ int lcur[256];
  __shared__ int ws[8];
  __shared__ unsigned int packed_s[4096];
  __shared__ unsigned char bucket_of[4096];
  const int tid = threadIdx.x;
  cnt[tid] = 0;
  __syncthreads();
  const int base = blockIdx.x * 4096;
  const int vn = min(4096, E - base);
#pragma unroll 4
  for (int j = 0; j < 16; j++) {
    int i = j * 256 + tid;
    if (i < vn) {
      int d = ei[E + base + i];
      d = min(max(d, 0), N - 1);
      atomicAdd(&cnt[d >> 8], 1);
    }
  }
  __syncthreads();
  int excl = block_scan256(cnt[tid], tid, ws);
  offs[tid] = excl;
  lcur[tid] = excl;
  int bb = block_scan256((tid < NB) ? bhist[tid] : 0, tid, ws);
  if (tid < NB && cnt[tid]) gbase[tid] = bb + atomicAdd(&bcur_rel[tid], cnt[tid]);
  __syncthreads();
#pragma unroll 4
  for (int j = 0; j < 16; j++) {
    int i = j * 256 + tid;
    if (i < vn) {
      int s = ei[base + i];
      int d = ei[E + base + i];
      s = min(max(s, 0), N - 1);
      d = min(max(d, 0), N - 1);
      int b = d >> 8;
      int slot = atomicAdd(&lcur[b], 1);
      packed_s[slot] = (unsigned)s | ((unsigned)(d & 255) << 16);
      bucket_of[slot] = (unsigned char)b;
    }
  }
  __syncthreads();
  for (int i = tid; i < vn; i += 256) {
    int b = bucket_of[i];
    pairs[gbase[b] + (i - offs[b])] = packed_s[i];
  }
}

// ---------------------------------------------------------------------------
// csr_fine: local re-scan of bhist gives pbase/pcnt.
// ---------------------------------------------------------------------------
__global__ __launch_bounds__(256) void csr_fine(
    const unsigned int* __restrict__ pairs, const int* __restrict__ bhist,
    int* __restrict__ row_ofs, int* __restrict__ src_sorted, int N, int E, int NB) {
  __shared__ int cnt[256];
  __shared__ int cursor[256];
  __shared__ int ws[8];
  __shared__ int pb[2];
  const int tid = threadIdx.x;
  const int b = blockIdx.x;
  const int d0 = b << 8;
  const int nd = min(256, N - d0);
  cnt[tid] = (tid < nd) ? 1 : 0;
  int bb = block_scan256((tid < NB) ? bhist[tid] : 0, tid, ws);
  if (tid == b) pb[0] = bb;
  if (tid == b + 1) pb[1] = bb;
  __syncthreads();
  const int pbase = pb[0];
  const int pcnt = pb[1] - pbase;
  const int row_base = pbase + d0;
  for (int i = tid; i < pcnt; i += 256) {
    unsigned p = pairs[pbase + i];
    atomicAdd(&cnt[(p >> 16) & 255], 1);
  }
  __syncthreads();
  int excl = block_scan256(cnt[tid], tid, ws);
  if (tid < nd) {
    row_ofs[d0 + tid] = row_base + excl;
    src_sorted[row_base + excl] = d0 + tid;
    cursor[tid] = excl + 1;
  }
  if (b == NB - 1 && tid == 0) row_ofs[N] = E + N;
  __syncthreads();
  for (int i = tid; i < pcnt; i += 256) {
    unsigned p = pairs[pbase + i];
    int dl = (p >> 16) & 255;
    int slot = atomicAdd(&cursor[dl], 1);
    src_sorted[row_base + slot] = (int)(p & 0xffffu);
  }
}

// ---------------------------------------------------------------------------
// Merged transform: Ys = X@Ws + bs, Yd = X@Wd + bd, outputs packed f16.
// CVT=1: Xin is fp32 (converted in-kernel, RTNE); CVT=0: Xin is packed f16.
// ---------------------------------------------------------------------------
template <int NT, int CVT>
__global__ __launch_bounds__(256) void mfma_xform2(
    const void* __restrict__ Xin,
    const unsigned short* __restrict__ BpS, const unsigned short* __restrict__ BpD,
    const float* __restrict__ bS, const float* __restrict__ bD,
    unsigned int* __restrict__ Ys, unsigned int* __restrict__ Yd, int M) {
  const int wave = threadIdx.x >> 6;
  const int lane = threadIdx.x & 63;
  const int row0 = blockIdx.x * 64 + wave * 16;
  const int m = lane & 15, q = lane >> 4;
  const int arow = min(row0 + m, M - 1);
  h8v a[4];
  if constexpr (CVT) {
    const float* xp = (const float*)Xin + (size_t)arow * 128 + q * 8;
#pragma unroll
    for (int kc = 0; kc < 4; kc++) {
      const float4 f0 = *(const float4*)(xp + kc * 32);
      const float4 f1 = *(const float4*)(xp + kc * 32 + 4);
      uint4 u;
      u.x = pk16(f0.x, f0.y); u.y = pk16(f0.z, f0.w);
      u.z = pk16(f1.x, f1.y); u.w = pk16(f1.z, f1.w);
      a[kc] = __builtin_bit_cast(h8v, u);
    }
  } else {
    const unsigned short* xp = (const unsigned short*)Xin + (size_t)arow * 128 + q * 8;
#pragma unroll
    for (int kc = 0; kc < 4; kc++) a[kc] = *(const h8v*)(xp + kc * 32);
  }
  float4v accS[NT], accD[NT];
#pragma unroll
  for (int t = 0; t < NT; t++) { accS[t] = (float4v)(0.f); accD[t] = (float4v)(0.f); }
#pragma unroll
  for (int kc = 0; kc < 4; kc++) {
#pragma unroll
    for (int t = 0; t < NT; t++) {
      h8v bs = *(const h8v*)(BpS + ((size_t)(t * 4 + kc) * 64 + lane) * 8);
      h8v bd = *(const h8v*)(BpD + ((size_t)(t * 4 + kc) * 64 + lane) * 8);
      accS[t] = __builtin_amdgcn_mfma_f32_16x16x32_f16(a[kc], bs, accS[t], 0, 0, 0);
      accD[t] = __builtin_amdgcn_mfma_f32_16x16x32_f16(a[kc], bd, accD[t], 0, 0, 0);
    }
  }
  const bool even = (m & 1) == 0;
#pragma unroll
  for (int t = 0; t < NT; t++) {
    const int col = t * 16 + m;
    const float bcS = bS[col], bcD = bD[col];
#pragma unroll
    for (int r = 0; r < 4; r++) {
      const int row = row0 + q * 4 + r;
      float vS = accS[t][r] + bcS;
      float vD = accD[t][r] + bcD;
      float pS = __shfl_xor(vS, 1);
      float pD = __shfl_xor(vD, 1);
      if (even && row < M) {
        size_t idx = (size_t)row * (NT * 8) + t * 8 + (m >> 1);
        Ys[idx] = pk16(vS, pS);
        Yd[idx] = pk16(vD, pD);
      }
    }
  }
}

// ---------------------------------------------------------------------------
// Layer-1 fused: one wave per dst node, 8 lanes/edge (lane j owns head j).
// 32-edge window: ALL of the window's gathers are issued upfront (independent
// loads -> 2-8 outstanding VMEM, progressive vmcnt) before any compute, then
// the 4 sub-iterations are processed. Collapses the dependent gather chain
// (~3 x L2/L3 latency per node) to ~1 x latency + compute.
// ---------------------------------------------------------------------------
__global__ __launch_bounds__(256) void gat1_fused(
    const int* __restrict__ row_ofs, const int* __restrict__ src_sorted,
    const unsigned int* __restrict__ xsb, const unsigned int* __restrict__ xdb,
    const float* __restrict__ att, const float* __restrict__ bias,
    unsigned int* __restrict__ h1b, int N) {
  const int node = (int)((blockIdx.x * 256u + threadIdx.x) >> 6);
  const int lane = threadIdx.x & 63;
  const int j = lane & 7;   // head index; channels 16j..16j+15
  const int g = lane >> 3;  // edge slot within sub-iteration (0..7)
  if (node >= N) return;
  h2v at2[8], xd[8];
  {
    const float4 a0 = *(const float4*)(att + 16 * j);
    const float4 a1 = *(const float4*)(att + 16 * j + 4);
    const float4 a2 = *(const float4*)(att + 16 * j + 8);
    const float4 a3 = *(const float4*)(att + 16 * j + 12);
    at2[0] = u2h(pk16(a0.x, a0.y)); at2[1] = u2h(pk16(a0.z, a0.w));
    at2[2] = u2h(pk16(a1.x, a1.y)); at2[3] = u2h(pk16(a1.z, a1.w));
    at2[4] = u2h(pk16(a2.x, a2.y)); at2[5] = u2h(pk16(a2.z, a2.w));
    at2[6] = u2h(pk16(a3.x, a3.y)); at2[7] = u2h(pk16(a3.z, a3.w));
    const uint4 x0 = *(const uint4*)(xdb + (unsigned)(node * 64 + 8 * j));
    const uint4 x1 = *(const uint4*)(xdb + (unsigned)(node * 64 + 8 * j + 4));
    xd[0] = u2h(x0.x); xd[1] = u2h(x0.y); xd[2] = u2h(x0.z); xd[3] = u2h(x0.w);
    xd[4] = u2h(x1.x); xd[5] = u2h(x1.y); xd[6] = u2h(x1.z); xd[7] = u2h(x1.w);
  }
  h2v ns; ns.x = (_Float16)NEG_SLOPE; ns.y = (_Float16)NEG_SLOPE;
  h2v acc[8];
#pragma unroll
  for (int i = 0; i < 8; i++) acc[i] = (h2v)((_Float16)0.f);
  float den = 0.f;
  const int b = row_ofs[node];
  const int cnt = row_ofs[node + 1] - b;

  auto process = [&](const uint4 c0, const uint4 c1, bool valid) {
    h2v m[8];
    m[0] = u2h(c0.x); m[1] = u2h(c0.y); m[2] = u2h(c0.z); m[3] = u2h(c0.w);
    m[4] = u2h(c1.x); m[5] = u2h(c1.y); m[6] = u2h(c1.z); m[7] = u2h(c1.w);
    float p = 0.f;
#pragma unroll
    for (int k = 0; k < 8; k++) {
      h2v t = m[k] + xd[k];
      h2v r = __builtin_elementwise_max(t, t * ns);
      p = fdot2(r, at2[k], p);
    }
    float ex = valid ? __expf(p) : 0.f;
    den += ex;
    h2v exh; exh.x = exh.y = (_Float16)ex;
#pragma unroll
    for (int k = 0; k < 8; k++) acc[k] += m[k] * exh;
  };

  for (int base = 0; base < cnt; base += 32) {
    const int ne = min(32, cnt - base);
    int sidx = (lane < ne) ? src_sorted[b + base + lane] : node;
    const int nIter = (ne + 7) >> 3;
    uint4 a0, b0, a1, b1, a2, b2, a3, b3;
    {
      int s = __shfl(sidx, g);
      a0 = *(const uint4*)(xsb + (unsigned)(s * 64 + 8 * j));
      b0 = *(const uint4*)(xsb + (unsigned)(s * 64 + 8 * j + 4));
    }
    if (nIter > 1) {
      int s = __shfl(sidx, 8 + g);
      a1 = *(const uint4*)(xsb + (unsigned)(s * 64 + 8 * j));
      b1 = *(const uint4*)(xsb + (unsigned)(s * 64 + 8 * j + 4));
    }
    if (nIter > 2) {
      int s = __shfl(sidx, 16 + g);
      a2 = *(const uint4*)(xsb + (unsigned)(s * 64 + 8 * j));
      b2 = *(const uint4*)(xsb + (unsigned)(s * 64 + 8 * j + 4));
    }
    if (nIter > 3) {
      int s = __shfl(sidx, 24 + g);
      a3 = *(const uint4*)(xsb + (unsigned)(s * 64 + 8 * j));
      b3 = *(const uint4*)(xsb + (unsigned)(s * 64 + 8 * j + 4));
    }
    process(a0, b0, g < ne);
    if (nIter > 1) process(a1, b1, 8 + g < ne);
    if (nIter > 2) process(a2, b2, 16 + g < ne);
    if (nIter > 3) process(a3, b3, 24 + g < ne);
  }
#pragma unroll
  for (int off = 8; off < 64; off <<= 1) {
#pragma unroll
    for (int i = 0; i < 8; i++) acc[i] += u2h(__shfl_xor(h2u(acc[i]), off));
    den += __shfl_xor(den, off);
  }
  if (lane < 8) {
    const float inv = 1.f / den;
    const float4 bc0 = *(const float4*)(bias + 16 * j);
    const float4 bc1 = *(const float4*)(bias + 16 * j + 4);
    const float4 bc2 = *(const float4*)(bias + 16 * j + 8);
    const float4 bc3 = *(const float4*)(bias + 16 * j + 12);
    float v[16];
    v[0]  = fmaf((float)acc[0].x, inv, bc0.x);
    v[1]  = fmaf((float)acc[0].y, inv, bc0.y);
    v[2]  = fmaf((float)acc[1].x, inv, bc0.z);
    v[3]  = fmaf((float)acc[1].y, inv, bc0.w);
    v[4]  = fmaf((float)acc[2].x, inv, bc1.x);
    v[5]  = fmaf((float)acc[2].y, inv, bc1.y);
    v[6]  = fmaf((float)acc[3].x, inv, bc1.z);
    v[7]  = fmaf((float)acc[3].y, inv, bc1.w);
    v[8]  = fmaf((float)acc[4].x, inv, bc2.x);
    v[9]  = fmaf((float)acc[4].y, inv, bc2.y);
    v[10] = fmaf((float)acc[5].x, inv, bc2.z);
    v[11] = fmaf((float)acc[5].y, inv, bc2.w);
    v[12] = fmaf((float)acc[6].x, inv, bc3.x);
    v[13] = fmaf((float)acc[6].y, inv, bc3.y);
    v[14] = fmaf((float)acc[7].x, inv, bc3.z);
    v[15] = fmaf((float)acc[7].y, inv, bc3.w);
#pragma unroll
    for (int k = 0; k < 16; k++) v[k] = v[k] > 0.f ? v[k] : __expf(v[k]) - 1.f;
    uint4 o0, o1;
    o0.x = pk16(v[0], v[1]);   o0.y = pk16(v[2], v[3]);
    o0.z = pk16(v[4], v[5]);   o0.w = pk16(v[6], v[7]);
    o1.x = pk16(v[8], v[9]);   o1.y = pk16(v[10], v[11]);
    o1.z = pk16(v[12], v[13]); o1.w = pk16(v[14], v[15]);
    *(uint4*)(h1b + (unsigned)(node * 64 + 8 * j)) = o0;
    *(uint4*)(h1b + (unsigned)(node * 64 + 8 * j + 4)) = o1;
  }
}

// ---------------------------------------------------------------------------
// Layer-2 fused: one wave per dst node, 4 lanes/edge, 64-edge window with all
// gathers issued upfront (same latency collapse). + log_softmax epilogue.
// ---------------------------------------------------------------------------
__global__ __launch_bounds__(256) void gat2_fused(
    const int* __restrict__ row_ofs, const int* __restrict__ src_sorted,
    const unsigned int* __restrict__ xsb, const unsigned int* __restrict__ xdb,
    const float* __restrict__ att, const float* __restrict__ bias,
    float* __restrict__ out, int N) {
  const int node = (int)((blockIdx.x * 256u + threadIdx.x) >> 6);
  const int lane = threadIdx.x & 63;
  const int l = lane & 3;
  const int g = lane >> 2;
  if (node >= N) return;
  h2v at2[4], xd[4];
  {
    const float4 a01 = *(const float4*)(att + 8 * l);
    const float4 a23 = *(const float4*)(att + 8 * l + 4);
    at2[0] = u2h(pk16(a01.x, a01.y)); at2[1] = u2h(pk16(a01.z, a01.w));
    at2[2] = u2h(pk16(a23.x, a23.y)); at2[3] = u2h(pk16(a23.z, a23.w));
    const uint4 xdp = *(const uint4*)(xdb + (unsigned)(node * 16 + 4 * l));
    xd[0] = u2h(xdp.x); xd[1] = u2h(xdp.y);
    xd[2] = u2h(xdp.z); xd[3] = u2h(xdp.w);
  }
  h2v ns; ns.x = (_Float16)NEG_SLOPE; ns.y = (_Float16)NEG_SLOPE;
  h2v acc[4];
#pragma unroll
  for (int i = 0; i < 4; i++) acc[i] = (h2v)((_Float16)0.f);
  float den = 0.f;
  const int b = row_ofs[node];
  const int cnt = row_ofs[node + 1] - b;

  auto process = [&](const uint4 cur, bool valid) {
    const h2v m0 = u2h(cur.x), m1 = u2h(cur.y), m2 = u2h(cur.z), m3 = u2h(cur.w);
    h2v t0 = m0 + xd[0]; h2v r0 = __builtin_elementwise_max(t0, t0 * ns);
    h2v t1 = m1 + xd[1]; h2v r1 = __builtin_elementwise_max(t1, t1 * ns);
    h2v t2 = m2 + xd[2]; h2v r2 = __builtin_elementwise_max(t2, t2 * ns);
    h2v t3 = m3 + xd[3]; h2v r3 = __builtin_elementwise_max(t3, t3 * ns);
    float p = fdot2(r0, at2[0], 0.f);
    p = fdot2(r1, at2[1], p);
    p = fdot2(r2, at2[2], p);
    p = fdot2(r3, at2[3], p);
    p += __shfl_xor(p, 1);
    p += __shfl_xor(p, 2);
    float ex = valid ? __expf(p) : 0.f;
    den += ex;
    h2v exh; exh.x = exh.y = (_Float16)ex;
    acc[0] += m0 * exh;
    acc[1] += m1 * exh;
    acc[2] += m2 * exh;
    acc[3] += m3 * exh;
  };

  for (int base = 0; base < cnt; base += 64) {
    const int ne = min(64, cnt - base);
    int sidx = (lane < ne) ? src_sorted[b + base + lane] : node;
    const int nIter = (ne + 15) >> 4;
    uint4 m0, m1, m2, m3;
    {
      int s = __shfl(sidx, g);
      m0 = *(const uint4*)(xsb + (unsigned)(s * 16 + 4 * l));
    }
    if (nIter > 1) {
      int s = __shfl(sidx, 16 + g);
      m1 = *(const uint4*)(xsb + (unsigned)(s * 16 + 4 * l));
    }
    if (nIter > 2) {
      int s = __shfl(sidx, 32 + g);
      m2 = *(const uint4*)(xsb + (unsigned)(s * 16 + 4 * l));
    }
    if (nIter > 3) {
      int s = __shfl(sidx, 48 + g);
      m3 = *(const uint4*)(xsb + (unsigned)(s * 16 + 4 * l));
    }
    process(m0, g < ne);
    if (nIter > 1) process(m1, 16 + g < ne);
    if (nIter > 2) process(m2, 32 + g < ne);
    if (nIter > 3) process(m3, 48 + g < ne);
  }
#pragma unroll
  for (int off = 4; off < 64; off <<= 1) {
#pragma unroll
    for (int i = 0; i < 4; i++) acc[i] += u2h(__shfl_xor(h2u(acc[i]), off));
    den += __shfl_xor(den, off);
  }
  if (lane < 4) {
    const float inv = 1.f / den;
    const float4 bc01 = *(const float4*)(bias + 8 * l);
    const float4 bc23 = *(const float4*)(bias + 8 * l + 4);
    float v0 = fmaf((float)acc[0].x, inv, bc01.x);
    float v1 = fmaf((float)acc[0].y, inv, bc01.y);
    float v2 = fmaf((float)acc[1].x, inv, bc01.z);
    float v3 = fmaf((float)acc[1].y, inv, bc01.w);
    float v4 = fmaf((float)acc[2].x, inv, bc23.x);
    float v5 = fmaf((float)acc[2].y, inv, bc23.y);
    float v6 = fmaf((float)acc[3].x, inv, bc23.z);
    float v7 = fmaf((float)acc[3].y, inv, bc23.w);
    float mx = fmaxf(fmaxf(fmaxf(v0, v1), fmaxf(v2, v3)),
                     fmaxf(fmaxf(v4, v5), fmaxf(v6, v7)));
    mx = fmaxf(mx, __shfl_xor(mx, 1));
    mx = fmaxf(mx, __shfl_xor(mx, 2));
    float sum = __expf(v0 - mx) + __expf(v1 - mx) + __expf(v2 - mx) +
                __expf(v3 - mx) + __expf(v4 - mx) + __expf(v5 - mx) +
                __expf(v6 - mx) + __expf(v7 - mx);
    sum += __shfl_xor(sum, 1);
    sum += __shfl_xor(sum, 2);
    const float lse = mx + __logf(sum);
    float* op = out + (size_t)node * 32 + 8 * l;
    *(float4*)op = make_float4(v0 - lse, v1 - lse, v2 - lse, v3 - lse);
    *(float4*)(op + 4) = make_float4(v4 - lse, v5 - lse, v6 - lse, v7 - lse);
  }
}

extern "C" void kernel_launch(void* const* d_in, const int* in_sizes, int n_in,
                              void* d_out, int out_size, void* d_ws, size_t ws_size,
                              hipStream_t stream) {
  const float* x = (const float*)d_in[0];
  const int* ei = (const int*)d_in[1];
  const float* W1s = (const float*)d_in[2];
  const float* W1d = (const float*)d_in[3];
  const float* b1s = (const float*)d_in[4];
  const float* b1d = (const float*)d_in[5];
  const float* att1 = (const float*)d_in[6];
  const float* bias1 = (const float*)d_in[7];
  const float* W2s = (const float*)d_in[8];
  const float* W2d = (const float*)d_in[9];
  const float* b2s = (const float*)d_in[10];
  const float* b2d = (const float*)d_in[11];
  const float* att2 = (const float*)d_in[12];
  const float* bias2 = (const float*)d_in[13];
  float* out = (float*)d_out;

  const int N = in_sizes[0] / 128;
  const int E = in_sizes[1] / 2;
  const int NB = (N + 255) >> 8;

  char* p = (char*)d_ws;
  auto alloc = [&](size_t bytes) { char* r = p; p += (bytes + 63) & ~63ull; return r; };
  unsigned int* xs1b = (unsigned int*)alloc((size_t)N * 64 * 4);
  unsigned int* xd1b = (unsigned int*)alloc((size_t)N * 64 * 4);
  unsigned int* xs2b = (unsigned int*)alloc((size_t)N * 16 * 4);
  unsigned int* xd2b = (unsigned int*)alloc((size_t)N * 16 * 4);
  unsigned int* h1b = (unsigned int*)alloc((size_t)N * 64 * 4);
  unsigned short* Bp1s = (unsigned short*)alloc(8 * 4 * 64 * 8 * 2);
  unsigned short* Bp1d = (unsigned short*)alloc(8 * 4 * 64 * 8 * 2);
  unsigned short* Bp2s = (unsigned short*)alloc(2 * 4 * 64 * 8 * 2);
  unsigned short* Bp2d = (unsigned short*)alloc(2 * 4 * 64 * 8 * 2);
  int* bhist = (int*)alloc(512 * 4);  // [0..255]=bhist, [256..511]=bcur_rel
  int* bcur_rel = bhist + 256;
  unsigned int* pairs = (unsigned int*)alloc((size_t)E * 4);
  int* row_ofs = (int*)alloc((size_t)(N + 1) * 4);
  int* src_sorted = (int*)alloc((size_t)(E + N) * 4);

  hipMemsetAsync(bhist, 0, 512 * sizeof(int), stream);

  const int nA = (E + 4095) / 4096;
  pack_hist<<<20 + nA, 256, 0, stream>>>(W1s, W1d, W2s, W2d, Bp1s, Bp1d, Bp2s, Bp2d,
                                         ei, bhist, N, E, NB);
  bucket_sort<<<nA, 256, 0, stream>>>(ei, bhist, bcur_rel, pairs, N, E, NB);
  csr_fine<<<NB, 256, 0, stream>>>(pairs, bhist, row_ofs, src_sorted, N, E, NB);

  const int xblocks = (N + 63) / 64;
  mfma_xform2<8, 1><<<xblocks, 256, 0, stream>>>(x, Bp1s, Bp1d, b1s, b1d, xs1b, xd1b, N);

  gat1_fused<<<(N + 3) / 4, 256, 0, stream>>>(row_ofs, src_sorted, xs1b, xd1b,
                                              att1, bias1, h1b, N);

  mfma_xform2<2, 0><<<xblocks, 256, 0, stream>>>(h1b, Bp2s, Bp2d, b2s, b2d,
                                                 xs2b, xd2b, N);

  gat2_fused<<<(N + 3) / 4, 256, 0, stream>>>(row_ofs, src_sorted, xs2b, xd2b,
                                              att2, bias2, out, N);
}

// Round 8
// 202.936 us; speedup vs baseline: 1.1175x; 1.1175x over previous
//
#include <hip/hip_runtime.h>
#include <math.h>

#define NEG_SLOPE 0.2f

typedef __attribute__((ext_vector_type(8))) _Float16 h8v;
typedef __attribute__((ext_vector_type(2))) _Float16 h2v;
typedef __attribute__((ext_vector_type(4))) float float4v;

__device__ __forceinline__ h2v u2h(unsigned u) { return __builtin_bit_cast(h2v, u); }
__device__ __forceinline__ unsigned h2u(h2v h) { return __builtin_bit_cast(unsigned, h); }
// RTNE pack of two f32 -> packed f16x2 (v_cvt_f16_f32 x2 + v_pack_b32_f16)
__device__ __forceinline__ unsigned pk16(float a, float b) {
  h2v r; r.x = (_Float16)a; r.y = (_Float16)b;
  return __builtin_bit_cast(unsigned, r);
}
__device__ __forceinline__ unsigned short f16b(float f) {
  return __builtin_bit_cast(unsigned short, (_Float16)f);
}
// f32 += f16x2 . f16x2  (v_dot2_f32_f16, one issue slot for 2 MACs)
__device__ __forceinline__ float fdot2(h2v a, h2v b, float c) {
#if __has_builtin(__builtin_amdgcn_fdot2)
  return __builtin_amdgcn_fdot2(a, b, c, false);
#else
  return fmaf((float)a.x, (float)b.x, fmaf((float)a.y, (float)b.y, c));
#endif
}

// 256-wide block exclusive scan; all 256 threads must call. ws: >=8 ints LDS.
__device__ __forceinline__ int block_scan256(int v, int tid, int* ws) {
  const int lane = tid & 63, w = tid >> 6;
  int incl = v;
#pragma unroll
  for (int off = 1; off < 64; off <<= 1) {
    int t = __shfl_up(incl, off);
    if (lane >= off) incl += t;
  }
  if (lane == 63) ws[w] = incl;
  __syncthreads();
  if (tid == 0) {
    int s = 0;
#pragma unroll
    for (int i = 0; i < 4; i++) { int t = ws[i]; ws[4 + i] = s; s += t; }
  }
  __syncthreads();
  return incl - v + ws[4 + w];
}

// ---------------------------------------------------------------------------
// Fused: blocks 0..19 pack the 4 weight matrices into MFMA B-fragment layout;
// blocks 20.. run the coarse bucket histogram (4096 edges/block).
// ---------------------------------------------------------------------------
__global__ __launch_bounds__(256) void pack_hist(
    const float* __restrict__ W1s, const float* __restrict__ W1d,
    const float* __restrict__ W2s, const float* __restrict__ W2d,
    unsigned short* __restrict__ B1s, unsigned short* __restrict__ B1d,
    unsigned short* __restrict__ B2s, unsigned short* __restrict__ B2d,
    const int* __restrict__ ei, int* __restrict__ bhist, int N, int E, int NB) {
  int blk = blockIdx.x;
  if (blk < 20) {
    const float* W; unsigned short* Bp; int C, base;
    if (blk < 8)       { W = W1s; Bp = B1s; C = 128; base = blk; }
    else if (blk < 16) { W = W1d; Bp = B1d; C = 128; base = blk - 8; }
    else if (blk < 18) { W = W2s; Bp = B2s; C = 32;  base = blk - 16; }
    else               { W = W2d; Bp = B2d; C = 32;  base = blk - 18; }
    int idx = base * 256 + threadIdx.x;
    int total = (C / 16) * 4 * 64;
    if (idx >= total) return;
    int lane = idx & 63;
    int kc = (idx >> 6) & 3;
    int t = idx >> 8;
    int n = t * 16 + (lane & 15);
    int k0 = kc * 32 + (lane >> 4) * 8;
    unsigned short* o = Bp + (size_t)idx * 8;
#pragma unroll
    for (int j = 0; j < 8; j++) o[j] = f16b(W[(size_t)(k0 + j) * C + n]);
    return;
  }
  blk -= 20;
  __shared__ int cnt[256];
  const int tid = threadIdx.x;
  cnt[tid] = 0;
  __syncthreads();
  const int base = blk * 4096;
  const int vn = min(4096, E - base);
#pragma unroll 4
  for (int j = 0; j < 16; j++) {
    int i = j * 256 + tid;
    if (i < vn) {
      int d = ei[E + base + i];
      d = min(max(d, 0), N - 1);
      atomicAdd(&cnt[d >> 8], 1);
    }
  }
  __syncthreads();
  if (tid < NB && cnt[tid]) atomicAdd(&bhist[tid], cnt[tid]);
}

// ---------------------------------------------------------------------------
// bucket_sort body (local re-scan of bhist; zero-based bcur_rel reservation).
// ---------------------------------------------------------------------------
__device__ __forceinline__ void bucket_sort_body(
    int blk, const int* __restrict__ ei, const int* __restrict__ bhist,
    int* __restrict__ bcur_rel, unsigned int* __restrict__ pairs,
    int N, int E, int NB) {
  __shared__ int cnt[256];
  __shared__ int offs[256];
  __shared__ int gbase[256];
  __shared__ int lcur[256];
  __shared__ int ws[8];
  __shared__ unsigned int packed_s[4096];
  __shared__ unsigned char bucket_of[4096];
  const int tid = threadIdx.x;
  cnt[tid] = 0;
  __syncthreads();
  const int base = blk * 4096;
  const int vn = min(4096, E - base);
#pragma unroll 4
  for (int j = 0; j < 16; j++) {
    int i = j * 256 + tid;
    if (i < vn) {
      int d = ei[E + base + i];
      d = min(max(d, 0), N - 1);
      atomicAdd(&cnt[d >> 8], 1);
    }
  }
  __syncthreads();
  int excl = block_scan256(cnt[tid], tid, ws);
  offs[tid] = excl;
  lcur[tid] = excl;
  int bb = block_scan256((tid < NB) ? bhist[tid] : 0, tid, ws);
  if (tid < NB && cnt[tid]) gbase[tid] = bb + atomicAdd(&bcur_rel[tid], cnt[tid]);
  __syncthreads();
#pragma unroll 4
  for (int j = 0; j < 16; j++) {
    int i = j * 256 + tid;
    if (i < vn) {
      int s = ei[base + i];
      int d = ei[E + base + i];
      s = min(max(s, 0), N - 1);
      d = min(max(d, 0), N - 1);
      int b = d >> 8;
      int slot = atomicAdd(&lcur[b], 1);
      packed_s[slot] = (unsigned)s | ((unsigned)(d & 255) << 16);
      bucket_of[slot] = (unsigned char)b;
    }
  }
  __syncthreads();
  for (int i = tid; i < vn; i += 256) {
    int b = bucket_of[i];
    pairs[gbase[b] + (i - offs[b])] = packed_s[i];
  }
}

// ---------------------------------------------------------------------------
// xform body: Ys = X@Ws + bs, Yd = X@Wd + bd, outputs packed f16.
// CVT=1: Xin fp32 (RTNE in-kernel); CVT=0: packed f16.
// ---------------------------------------------------------------------------
template <int NT, int CVT>
__device__ __forceinline__ void xform_body(
    int blk, const void* __restrict__ Xin,
    const unsigned short* __restrict__ BpS, const unsigned short* __restrict__ BpD,
    const float* __restrict__ bS, const float* __restrict__ bD,
    unsigned int* __restrict__ Ys, unsigned int* __restrict__ Yd, int M) {
  const int wave = threadIdx.x >> 6;
  const int lane = threadIdx.x & 63;
  const int row0 = blk * 64 + wave * 16;
  const int m = lane & 15, q = lane >> 4;
  const int arow = min(row0 + m, M - 1);
  h8v a[4];
  if constexpr (CVT) {
    const float* xp = (const float*)Xin + (size_t)arow * 128 + q * 8;
#pragma unroll
    for (int kc = 0; kc < 4; kc++) {
      const float4 f0 = *(const float4*)(xp + kc * 32);
      const float4 f1 = *(const float4*)(xp + kc * 32 + 4);
      uint4 u;
      u.x = pk16(f0.x, f0.y); u.y = pk16(f0.z, f0.w);
      u.z = pk16(f1.x, f1.y); u.w = pk16(f1.z, f1.w);
      a[kc] = __builtin_bit_cast(h8v, u);
    }
  } else {
    const unsigned short* xp = (const unsigned short*)Xin + (size_t)arow * 128 + q * 8;
#pragma unroll
    for (int kc = 0; kc < 4; kc++) a[kc] = *(const h8v*)(xp + kc * 32);
  }
  float4v accS[NT], accD[NT];
#pragma unroll
  for (int t = 0; t < NT; t++) { accS[t] = (float4v)(0.f); accD[t] = (float4v)(0.f); }
#pragma unroll
  for (int kc = 0; kc < 4; kc++) {
#pragma unroll
    for (int t = 0; t < NT; t++) {
      h8v bs = *(const h8v*)(BpS + ((size_t)(t * 4 + kc) * 64 + lane) * 8);
      h8v bd = *(const h8v*)(BpD + ((size_t)(t * 4 + kc) * 64 + lane) * 8);
      accS[t] = __builtin_amdgcn_mfma_f32_16x16x32_f16(a[kc], bs, accS[t], 0, 0, 0);
      accD[t] = __builtin_amdgcn_mfma_f32_16x16x32_f16(a[kc], bd, accD[t], 0, 0, 0);
    }
  }
  const bool even = (m & 1) == 0;
#pragma unroll
  for (int t = 0; t < NT; t++) {
    const int col = t * 16 + m;
    const float bcS = bS[col], bcD = bD[col];
#pragma unroll
    for (int r = 0; r < 4; r++) {
      const int row = row0 + q * 4 + r;
      float vS = accS[t][r] + bcS;
      float vD = accD[t][r] + bcD;
      float pS = __shfl_xor(vS, 1);
      float pD = __shfl_xor(vD, 1);
      if (even && row < M) {
        size_t idx = (size_t)row * (NT * 8) + t * 8 + (m >> 1);
        Ys[idx] = pk16(vS, pS);
        Yd[idx] = pk16(vD, pD);
      }
    }
  }
}

// ---------------------------------------------------------------------------
// Fused launch: blocks [0, nA) run bucket_sort; blocks [nA, nA+xblocks) run
// the layer-1 transform. The two are independent (both consume pack_hist
// output) and individually underfill the machine; fused they overlap.
// ---------------------------------------------------------------------------
__global__ __launch_bounds__(256) void sort_xform(
    const int* __restrict__ ei, const int* __restrict__ bhist,
    int* __restrict__ bcur_rel, unsigned int* __restrict__ pairs,
    const float* __restrict__ x,
    const unsigned short* __restrict__ Bp1s, const unsigned short* __restrict__ Bp1d,
    const float* __restrict__ b1s, const float* __restrict__ b1d,
    unsigned int* __restrict__ xs1b, unsigned int* __restrict__ xd1b,
    int N, int E, int NB, int nA) {
  if ((int)blockIdx.x < nA) {
    bucket_sort_body(blockIdx.x, ei, bhist, bcur_rel, pairs, N, E, NB);
    return;
  }
  xform_body<8, 1>(blockIdx.x - nA, x, Bp1s, Bp1d, b1s, b1d, xs1b, xd1b, N);
}

// Layer-2 transform as its own kernel.
__global__ __launch_bounds__(256) void mfma_xform_l2(
    const void* __restrict__ Xin,
    const unsigned short* __restrict__ BpS, const unsigned short* __restrict__ BpD,
    const float* __restrict__ bS, const float* __restrict__ bD,
    unsigned int* __restrict__ Ys, unsigned int* __restrict__ Yd, int M) {
  xform_body<2, 0>(blockIdx.x, Xin, BpS, BpD, bS, bD, Ys, Yd, M);
}

// ---------------------------------------------------------------------------
// csr_fine: local re-scan of bhist gives pbase/pcnt.
// ---------------------------------------------------------------------------
__global__ __launch_bounds__(256) void csr_fine(
    const unsigned int* __restrict__ pairs, const int* __restrict__ bhist,
    int* __restrict__ row_ofs, int* __restrict__ src_sorted, int N, int E, int NB) {
  __shared__ int cnt[256];
  __shared__ int cursor[256];
  __shared__ int ws[8];
  __shared__ int pb[2];
  const int tid = threadIdx.x;
  const int b = blockIdx.x;
  const int d0 = b << 8;
  const int nd = min(256, N - d0);
  cnt[tid] = (tid < nd) ? 1 : 0;
  int bb = block_scan256((tid < NB) ? bhist[tid] : 0, tid, ws);
  if (tid == b) pb[0] = bb;
  if (tid == b + 1) pb[1] = bb;
  __syncthreads();
  const int pbase = pb[0];
  const int pcnt = pb[1] - pbase;
  const int row_base = pbase + d0;
  for (int i = tid; i < pcnt; i += 256) {
    unsigned p = pairs[pbase + i];
    atomicAdd(&cnt[(p >> 16) & 255], 1);
  }
  __syncthreads();
  int excl = block_scan256(cnt[tid], tid, ws);
  if (tid < nd) {
    row_ofs[d0 + tid] = row_base + excl;
    src_sorted[row_base + excl] = d0 + tid;
    cursor[tid] = excl + 1;
  }
  if (b == NB - 1 && tid == 0) row_ofs[N] = E + N;
  __syncthreads();
  for (int i = tid; i < pcnt; i += 256) {
    unsigned p = pairs[pbase + i];
    int dl = (p >> 16) & 255;
    int slot = atomicAdd(&cursor[dl], 1);
    src_sorted[row_base + slot] = (int)(p & 0xffffu);
  }
}

// ---------------------------------------------------------------------------
// Layer-1 fused: one wave per dst node, 4 edges/iteration, 16 lanes/edge.
// Inner loop: pk_add/pk_mul/pk_max (LeakyReLU), v_dot2_f32_f16 (logit),
// v_pk_fma_f16 (weighted aggregate). Best-measured configuration (R5).
// ---------------------------------------------------------------------------
__global__ __launch_bounds__(256) void gat1_fused(
    const int* __restrict__ row_ofs, const int* __restrict__ src_sorted,
    const unsigned int* __restrict__ xsb, const unsigned int* __restrict__ xdb,
    const float* __restrict__ att, const float* __restrict__ bias,
    unsigned int* __restrict__ h1b, int N) {
  const int node = (int)((blockIdx.x * 256u + threadIdx.x) >> 6);
  const int lane = threadIdx.x & 63;
  const int l = lane & 15;
  const int g = lane >> 4;
  if (node >= N) return;
  h2v at2[4], xd[4];
  {
    const float4 a01 = *(const float4*)(att + 8 * l);
    const float4 a23 = *(const float4*)(att + 8 * l + 4);
    at2[0] = u2h(pk16(a01.x, a01.y)); at2[1] = u2h(pk16(a01.z, a01.w));
    at2[2] = u2h(pk16(a23.x, a23.y)); at2[3] = u2h(pk16(a23.z, a23.w));
    const uint4 xdp = *(const uint4*)(xdb + (unsigned)(node * 64 + 4 * l));
    xd[0] = u2h(xdp.x); xd[1] = u2h(xdp.y);
    xd[2] = u2h(xdp.z); xd[3] = u2h(xdp.w);
  }
  h2v ns; ns.x = (_Float16)NEG_SLOPE; ns.y = (_Float16)NEG_SLOPE;
  h2v acc[4];
#pragma unroll
  for (int i = 0; i < 4; i++) acc[i] = (h2v)((_Float16)0.f);
  float den = 0.f;
  const int b = row_ofs[node];
  const int cnt = row_ofs[node + 1] - b;
  for (int base = 0; base < cnt; base += 64) {
    const int rem = cnt - base;
    int sidx = (lane < rem) ? src_sorted[b + base + lane] : node;
    const int nIter = min(16, (rem + 3) >> 2);
    int s = __shfl(sidx, g);
    uint4 mp = *(const uint4*)(xsb + (unsigned)(s * 64 + 4 * l));
    for (int it = 0; it < nIter; it++) {
      const uint4 cur = mp;
      const bool v = (base + 4 * it + g) < cnt;
      if (it + 1 < nIter) {
        int sn = __shfl(sidx, 4 * (it + 1) + g);
        mp = *(const uint4*)(xsb + (unsigned)(sn * 64 + 4 * l));
      }
      const h2v m0 = u2h(cur.x), m1 = u2h(cur.y), m2 = u2h(cur.z), m3 = u2h(cur.w);
      h2v t0 = m0 + xd[0]; h2v r0 = __builtin_elementwise_max(t0, t0 * ns);
      h2v t1 = m1 + xd[1]; h2v r1 = __builtin_elementwise_max(t1, t1 * ns);
      h2v t2 = m2 + xd[2]; h2v r2 = __builtin_elementwise_max(t2, t2 * ns);
      h2v t3 = m3 + xd[3]; h2v r3 = __builtin_elementwise_max(t3, t3 * ns);
      float p = fdot2(r0, at2[0], 0.f);
      p = fdot2(r1, at2[1], p);
      p = fdot2(r2, at2[2], p);
      p = fdot2(r3, at2[3], p);
      p += __shfl_xor(p, 1);  // pair lanes share one head
      float ex = v ? __expf(p) : 0.f;
      den += ex;
      h2v exh; exh.x = exh.y = (_Float16)ex;
      acc[0] += m0 * exh;
      acc[1] += m1 * exh;
      acc[2] += m2 * exh;
      acc[3] += m3 * exh;
    }
  }
#pragma unroll
  for (int off = 16; off < 64; off <<= 1) {
#pragma unroll
    for (int i = 0; i < 4; i++) acc[i] += u2h(__shfl_xor(h2u(acc[i]), off));
    den += __shfl_xor(den, off);
  }
  if (lane < 16) {
    const float inv = 1.f / den;
    const float4 bc01 = *(const float4*)(bias + 8 * l);
    const float4 bc23 = *(const float4*)(bias + 8 * l + 4);
    float v0 = fmaf((float)acc[0].x, inv, bc01.x);
    float v1 = fmaf((float)acc[0].y, inv, bc01.y);
    float v2 = fmaf((float)acc[1].x, inv, bc01.z);
    float v3 = fmaf((float)acc[1].y, inv, bc01.w);
    float v4 = fmaf((float)acc[2].x, inv, bc23.x);
    float v5 = fmaf((float)acc[2].y, inv, bc23.y);
    float v6 = fmaf((float)acc[3].x, inv, bc23.z);
    float v7 = fmaf((float)acc[3].y, inv, bc23.w);
    v0 = v0 > 0.f ? v0 : __expf(v0) - 1.f;
    v1 = v1 > 0.f ? v1 : __expf(v1) - 1.f;
    v2 = v2 > 0.f ? v2 : __expf(v2) - 1.f;
    v3 = v3 > 0.f ? v3 : __expf(v3) - 1.f;
    v4 = v4 > 0.f ? v4 : __expf(v4) - 1.f;
    v5 = v5 > 0.f ? v5 : __expf(v5) - 1.f;
    v6 = v6 > 0.f ? v6 : __expf(v6) - 1.f;
    v7 = v7 > 0.f ? v7 : __expf(v7) - 1.f;
    uint4 o;
    o.x = pk16(v0, v1); o.y = pk16(v2, v3);
    o.z = pk16(v4, v5); o.w = pk16(v6, v7);
    *(uint4*)(h1b + (unsigned)(node * 64 + 4 * l)) = o;
  }
}

// ---------------------------------------------------------------------------
// Layer-2 fused: one wave per dst node, 16 edges/iteration, 4 lanes/edge.
// Same dot2/pk_fma inner loop. + log_softmax epilogue. (R5 configuration)
// ---------------------------------------------------------------------------
__global__ __launch_bounds__(256) void gat2_fused(
    const int* __restrict__ row_ofs, const int* __restrict__ src_sorted,
    const unsigned int* __restrict__ xsb, const unsigned int* __restrict__ xdb,
    const float* __restrict__ att, const float* __restrict__ bias,
    float* __restrict__ out, int N) {
  const int node = (int)((blockIdx.x * 256u + threadIdx.x) >> 6);
  const int lane = threadIdx.x & 63;
  const int l = lane & 3;
  const int g = lane >> 2;
  if (node >= N) return;
  h2v at2[4], xd[4];
  {
    const float4 a01 = *(const float4*)(att + 8 * l);
    const float4 a23 = *(const float4*)(att + 8 * l + 4);
    at2[0] = u2h(pk16(a01.x, a01.y)); at2[1] = u2h(pk16(a01.z, a01.w));
    at2[2] = u2h(pk16(a23.x, a23.y)); at2[3] = u2h(pk16(a23.z, a23.w));
    const uint4 xdp = *(const uint4*)(xdb + (unsigned)(node * 16 + 4 * l));
    xd[0] = u2h(xdp.x); xd[1] = u2h(xdp.y);
    xd[2] = u2h(xdp.z); xd[3] = u2h(xdp.w);
  }
  h2v ns; ns.x = (_Float16)NEG_SLOPE; ns.y = (_Float16)NEG_SLOPE;
  h2v acc[4];
#pragma unroll
  for (int i = 0; i < 4; i++) acc[i] = (h2v)((_Float16)0.f);
  float den = 0.f;
  const int b = row_ofs[node];
  const int cnt = row_ofs[node + 1] - b;
  for (int base = 0; base < cnt; base += 64) {
    const int rem = cnt - base;
    int sidx = (lane < rem) ? src_sorted[b + base + lane] : node;
    const int nIter = min(4, (rem + 15) >> 4);
    int s = __shfl(sidx, g);
    uint4 mp = *(const uint4*)(xsb + (unsigned)(s * 16 + 4 * l));
    for (int it = 0; it < nIter; it++) {
      const uint4 cur = mp;
      const bool v = (base + 16 * it + g) < cnt;
      if (it + 1 < nIter) {
        int sn = __shfl(sidx, 16 * (it + 1) + g);
        mp = *(const uint4*)(xsb + (unsigned)(sn * 16 + 4 * l));
      }
      const h2v m0 = u2h(cur.x), m1 = u2h(cur.y), m2 = u2h(cur.z), m3 = u2h(cur.w);
      h2v t0 = m0 + xd[0]; h2v r0 = __builtin_elementwise_max(t0, t0 * ns);
      h2v t1 = m1 + xd[1]; h2v r1 = __builtin_elementwise_max(t1, t1 * ns);
      h2v t2 = m2 + xd[2]; h2v r2 = __builtin_elementwise_max(t2, t2 * ns);
      h2v t3 = m3 + xd[3]; h2v r3 = __builtin_elementwise_max(t3, t3 * ns);
      float p = fdot2(r0, at2[0], 0.f);
      p = fdot2(r1, at2[1], p);
      p = fdot2(r2, at2[2], p);
      p = fdot2(r3, at2[3], p);
      p += __shfl_xor(p, 1);
      p += __shfl_xor(p, 2);
      float ex = v ? __expf(p) : 0.f;
      den += ex;
      h2v exh; exh.x = exh.y = (_Float16)ex;
      acc[0] += m0 * exh;
      acc[1] += m1 * exh;
      acc[2] += m2 * exh;
      acc[3] += m3 * exh;
    }
  }
#pragma unroll
  for (int off = 4; off < 64; off <<= 1) {
#pragma unroll
    for (int i = 0; i < 4; i++) acc[i] += u2h(__shfl_xor(h2u(acc[i]), off));
    den += __shfl_xor(den, off);
  }
  if (lane < 4) {
    const float inv = 1.f / den;
    const float4 bc01 = *(const float4*)(bias + 8 * l);
    const float4 bc23 = *(const float4*)(bias + 8 * l + 4);
    float v0 = fmaf((float)acc[0].x, inv, bc01.x);
    float v1 = fmaf((float)acc[0].y, inv, bc01.y);
    float v2 = fmaf((float)acc[1].x, inv, bc01.z);
    float v3 = fmaf((float)acc[1].y, inv, bc01.w);
    float v4 = fmaf((float)acc[2].x, inv, bc23.x);
    float v5 = fmaf((float)acc[2].y, inv, bc23.y);
    float v6 = fmaf((float)acc[3].x, inv, bc23.z);
    float v7 = fmaf((float)acc[3].y, inv, bc23.w);
    float mx = fmaxf(fmaxf(fmaxf(v0, v1), fmaxf(v2, v3)),
                     fmaxf(fmaxf(v4, v5), fmaxf(v6, v7)));
    mx = fmaxf(mx, __shfl_xor(mx, 1));
    mx = fmaxf(mx, __shfl_xor(mx, 2));
    float sum = __expf(v0 - mx) + __expf(v1 - mx) + __expf(v2 - mx) +
                __expf(v3 - mx) + __expf(v4 - mx) + __expf(v5 - mx) +
                __expf(v6 - mx) + __expf(v7 - mx);
    sum += __shfl_xor(sum, 1);
    sum += __shfl_xor(sum, 2);
    const float lse = mx + __logf(sum);
    float* op = out + (size_t)node * 32 + 8 * l;
    *(float4*)op = make_float4(v0 - lse, v1 - lse, v2 - lse, v3 - lse);
    *(float4*)(op + 4) = make_float4(v4 - lse, v5 - lse, v6 - lse, v7 - lse);
  }
}

extern "C" void kernel_launch(void* const* d_in, const int* in_sizes, int n_in,
                              void* d_out, int out_size, void* d_ws, size_t ws_size,
                              hipStream_t stream) {
  const float* x = (const float*)d_in[0];
  const int* ei = (const int*)d_in[1];
  const float* W1s = (const float*)d_in[2];
  const float* W1d = (const float*)d_in[3];
  const float* b1s = (const float*)d_in[4];
  const float* b1d = (const float*)d_in[5];
  const float* att1 = (const float*)d_in[6];
  const float* bias1 = (const float*)d_in[7];
  const float* W2s = (const float*)d_in[8];
  const float* W2d = (const float*)d_in[9];
  const float* b2s = (const float*)d_in[10];
  const float* b2d = (const float*)d_in[11];
  const float* att2 = (const float*)d_in[12];
  const float* bias2 = (const float*)d_in[13];
  float* out = (float*)d_out;

  const int N = in_sizes[0] / 128;
  const int E = in_sizes[1] / 2;
  const int NB = (N + 255) >> 8;

  char* p = (char*)d_ws;
  auto alloc = [&](size_t bytes) { char* r = p; p += (bytes + 63) & ~63ull; return r; };
  unsigned int* xs1b = (unsigned int*)alloc((size_t)N * 64 * 4);
  unsigned int* xd1b = (unsigned int*)alloc((size_t)N * 64 * 4);
  unsigned int* xs2b = (unsigned int*)alloc((size_t)N * 16 * 4);
  unsigned int* xd2b = (unsigned int*)alloc((size_t)N * 16 * 4);
  unsigned int* h1b = (unsigned int*)alloc((size_t)N * 64 * 4);
  unsigned short* Bp1s = (unsigned short*)alloc(8 * 4 * 64 * 8 * 2);
  unsigned short* Bp1d = (unsigned short*)alloc(8 * 4 * 64 * 8 * 2);
  unsigned short* Bp2s = (unsigned short*)alloc(2 * 4 * 64 * 8 * 2);
  unsigned short* Bp2d = (unsigned short*)alloc(2 * 4 * 64 * 8 * 2);
  int* bhist = (int*)alloc(512 * 4);  // [0..255]=bhist, [256..511]=bcur_rel
  int* bcur_rel = bhist + 256;
  unsigned int* pairs = (unsigned int*)alloc((size_t)E * 4);
  int* row_ofs = (int*)alloc((size_t)(N + 1) * 4);
  int* src_sorted = (int*)alloc((size_t)(E + N) * 4);

  hipMemsetAsync(bhist, 0, 512 * sizeof(int), stream);

  const int nA = (E + 4095) / 4096;
  const int xblocks = (N + 63) / 64;

  pack_hist<<<20 + nA, 256, 0, stream>>>(W1s, W1d, W2s, W2d, Bp1s, Bp1d, Bp2s, Bp2d,
                                         ei, bhist, N, E, NB);

  // bucket_sort (nA blocks) and layer-1 transform (xblocks) are independent:
  // one fused launch overlaps the underutilized sort with the dense xform.
  sort_xform<<<nA + xblocks, 256, 0, stream>>>(ei, bhist, bcur_rel, pairs,
                                               x, Bp1s, Bp1d, b1s, b1d,
                                               xs1b, xd1b, N, E, NB, nA);

  csr_fine<<<NB, 256, 0, stream>>>(pairs, bhist, row_ofs, src_sorted, N, E, NB);

  gat1_fused<<<(N + 3) / 4, 256, 0, stream>>>(row_ofs, src_sorted, xs1b, xd1b,
                                              att1, bias1, h1b, N);

  mfma_xform_l2<<<xblocks, 256, 0, stream>>>(h1b, Bp2s, Bp2d, b2s, b2d,
                                             xs2b, xd2b, N);

  gat2_fused<<<(N + 3) / 4, 256, 0, stream>>>(row_ofs, src_sorted, xs2b, xd2b,
                                              att2, bias2, out, N);
}